// Round 12
// baseline (140.931 us; speedup 1.0000x reference)
//
#include <hip/hip_runtime.h>
#include <stdint.h>

// TopoAELoss: two dense-graph MSTs (Boruvka) + sum of squared weight
// differences over both MST edge sets.
//
// R22 change: eliminate finalize_k. tile_k now atomicMins each row-chunk
// min directly into best[] (64 distinct addresses per wave -> no lane
// contention; non-returning global_atomic_min_x2, hidden under streaming
// reads). Robustness to poisoned d_ws (previously provided by finalize's
// unconditional store) moves to a 1-block init_k that pre-stores
// best=~0ull + done/out before tile_k. Also: triangular tile grid
// (2x2080 blocks, closed-form (r,c) from t) replaces the 2x4096 grid
// where half the blocks exited immediately. Saves the 8 MB cand re-read,
// one 2048-block dispatch, and ~4000 no-op block dispatches.
//
// R21 lesson: racy in-place pointer jumping in contract is correct and
// slightly faster (136.5 -> 135.4). Contract is ~2.5us/launch — small.
// R20 lesson: no dependent-load fast paths in front of slow-path rows.
// R19/R18 lesson: do NOT fuse contraction via last-block/arrival
// patterns — flat serial-tail pathology; graph launches are sub-us.
// R17 lesson: symmetric 64x64-tile cold scan halved cold bytes ->
// 166.5 -> 136.5us. ~3.1 TB/s is the empirical READ ceiling (write-only
// hits 6.7; copy = 3.15R+3.15W); tile_k's 66 MB triangle is byte-minimal.
// R16 lesson: rank-2 candidate cache null (deaths correlated).
// R15 lesson: scan throughput tracks occupancy; keep VGPR small.
// R14 lesson: burst load hoisting regressed. Keep rolled loops.
// R13 lesson: ROUNDS must be 12 = ceil(log2(4096)) — harness re-poisons
// inputs for the post-timing check. NEVER lower below 12.
// R11 lesson: per-lane CONTIGUOUS global rescans destroy coalescing; any
// contiguous range must be read wave/quarter-cooperatively.
// R10 lesson: do NOT fuse contraction into the scan kernel.
//
// Layout of d_ws (~4.3 MiB):
//   best : 2*4096 u64  @ 0       (65536 B)
//   comp : 2*4096 i32  @ 65536   (32768 B)
//   done : 2     i32   @ 98304   (8 B)
//   cand : 2*4096*64 u64 @ 98312 (4 MiB)   per-(row,64col-chunk) best edge

#define NPTS 4096
#define NCHUNK 64                   // contiguous 64-col chunks per row
#define NBLK 1024                   // warm blocks per problem (4 rows each)
#define NTRI 2080                   // 64*65/2 upper-triangle tiles
#define ROUNDS 12                   // ceil(log2(4096)) — sufficient for ANY
                                    // input. NEVER lower below 12.

typedef unsigned long long u64;

__device__ __forceinline__ u64 umin64(u64 a, u64 b) { return a < b ? a : b; }

// [ w_bits:32 | min(i,j):12 | max(i,j):12 ] — strict total order, symmetric.
__device__ __forceinline__ u64 pack_edge(float w, int i, int j) {
    unsigned wb = __float_as_uint(w);
    int u = i < j ? i : j;
    int v = i < j ? j : i;
    return ((u64)wb << 24) | ((u64)(unsigned)u << 12) | (u64)(unsigned)v;
}

__device__ __forceinline__ u64 wave_min64(u64 v) {
    #pragma unroll
    for (int off = 32; off; off >>= 1)
        v = umin64(v, __shfl_down(v, (unsigned)off, 64));
    return v;   // valid in lane 0
}

// Pre-store best=~0ull (atomicMin target), zero done/out. 1 block.
// Runs before tile_k every call -> robust to poisoned d_ws.
__global__ __launch_bounds__(1024) void init_k(
    u64* __restrict__ best, int* __restrict__ done, float* __restrict__ out) {
    int t = threadIdx.x;
    #pragma unroll
    for (int s = 0; s < 8; ++s) best[t + s * 1024] = ~0ull;
    if (t == 0) { done[0] = 0; done[1] = 0; out[0] = 0.f; }
}

// Cold tile scan: one block per upper-triangle 64x64 tile (triangular
// grid, closed-form r,c). Load tile to LDS (coalesced float4). wave0:
// per-row argmin -> cand[R0+l][c] + atomicMin(best[R0+l]). wave1 (r<c):
// per-col argmin -> cand[C0+l][r] + atomicMin(best[C0+l]) (valid by
// symmetry). Diagonal tiles exclude j==i and skip wave1.
__global__ __launch_bounds__(256) void tile_k(
    const float* __restrict__ D1, const float* __restrict__ D2,
    u64* __restrict__ cand, u64* __restrict__ best) {
    int pb = (blockIdx.x >= NTRI);
    int t  = blockIdx.x - pb * NTRI;
    // invert t = r*(129-r)/2 + (c-r):  r from float sqrt, then exact fixup
    int r = (int)((129.0f - sqrtf(16641.0f - 8.0f * (float)t)) * 0.5f);
    if (r > 63) r = 63;
    while (r * (129 - r) / 2 > t) --r;                  // float-precision fixup
    while ((r + 1) * (128 - r) / 2 <= t) ++r;
    int c = r + (t - r * (129 - r) / 2);
    const float* __restrict__ D = pb ? D2 : D1;
    u64* __restrict__ cnd = cand + (size_t)pb * NPTS * NCHUNK;
    u64* __restrict__ bst = best + pb * NPTS;

    __shared__ float ts[64][65];    // pad 65: banks (row+col)%32 -> 2-way, free
    int R0 = r << 6, C0 = c << 6;
    int tid = threadIdx.x;

    #pragma unroll
    for (int e = 0; e < 4; ++e) {
        int idx4 = tid + e * 256;
        int row = idx4 >> 4, c4 = idx4 & 15;
        const float4* __restrict__ rp =
            (const float4*)(D + (size_t)(R0 + row) * NPTS + C0);
        float4 w = rp[c4];
        ts[row][c4 * 4    ] = w.x; ts[row][c4 * 4 + 1] = w.y;
        ts[row][c4 * 4 + 2] = w.z; ts[row][c4 * 4 + 3] = w.w;
    }
    __syncthreads();

    int wave = tid >> 6, lane = tid & 63;
    if (wave == 0) {
        int i = R0 + lane;
        float wm = 3.4e38f; int jm = 0;
        if (r == c) {
            for (int j = 0; j < 64; ++j) {
                float x = ts[lane][j];
                if ((C0 + j) != i && x < wm) { wm = x; jm = C0 + j; }
            }
        } else {
            for (int j = 0; j < 64; ++j) {
                float x = ts[lane][j];
                if (x < wm) { wm = x; jm = C0 + j; }
            }
        }
        u64 e = pack_edge(wm, i, jm);
        cnd[i * NCHUNK + c] = e;
        atomicMin(&bst[i], e);          // 64 distinct addrs/wave, no contention
    } else if (wave == 1 && r != c) {
        int jcol = C0 + lane;
        float wm = 3.4e38f; int im = 0;
        for (int k2 = 0; k2 < 64; ++k2) {
            float x = ts[k2][lane];
            if (x < wm) { wm = x; im = R0 + k2; }
        }
        u64 e = pack_edge(wm, jcol, im);
        cnd[jcol * NCHUNK + r] = e;
        atomicMin(&bst[jcol], e);
    }
}

// Warm scan: 1 row per wave. Lane l validates cand[i][l] (far endpoint
// still external -> still exact; components only grow). Dead chunks are
// rescanned cooperatively: 4 chunks per pass, one quarter-wave each
// (16 lanes x float4 = 256B coalesced), 4-step shfl reduce, refresh cand.
// ~0ull rescan result = chunk permanently internal. One wave_min64/row.
__global__ __launch_bounds__(256) void warm_k(
    const float* __restrict__ D1, const float* __restrict__ D2,
    u64* __restrict__ best, const int* __restrict__ comp,
    const int* __restrict__ done, u64* __restrict__ cand) {
    int pb = blockIdx.x >> 10;
    if (done[pb]) return;
    int rb = blockIdx.x & (NBLK - 1);
    const float* __restrict__ D = pb ? D2 : D1;
    const int* __restrict__ cmpg = comp + pb * NPTS;
    u64* __restrict__ bst = best + pb * NPTS;
    u64* __restrict__ cnd = cand + (size_t)pb * NPTS * NCHUNK;

    int wave = threadIdx.x >> 6, lane = threadIdx.x & 63;
    int i = rb * 4 + wave;
    int ci = cmpg[i];

    u64 live = ~0ull;
    bool dead = false;
    u64 c = cnd[i * NCHUNK + lane];      // coalesced 64-lane load
    if (c != ~0ull) {                    // ~0ull: chunk permanently all-internal
        int u = (int)((c >> 12) & 0xFFF), v = (int)(c & 0xFFF);
        int j = (u == i) ? v : u;
        if (cmpg[j] != ci) live = c;     // still external -> still exact
        else dead = true;
    }

    u64 extra = ~0ull;
    u64 mask = __ballot(dead);           // wave-uniform
    if (mask) {
        const float4* __restrict__ rowf = (const float4*)(D + (size_t)i * NPTS);
        const int4* __restrict__ cmp4 = (const int4*)cmpg;
        int g = lane >> 4, m16 = lane & 15;
        while (mask) {
            int kq = -1;                 // chunk assigned to my quarter
            #pragma unroll
            for (int s = 0; s < 4; ++s) {
                int kk = mask ? (int)(__ffsll((long long)mask) - 1) : -1;
                if (kk >= 0) mask &= mask - 1;
                if (s == g) kq = kk;
            }
            u64 e = ~0ull;
            if (kq >= 0) {
                float4 w = rowf[kq * 16 + m16];      // 256B coalesced/quarter
                int4 cj = cmp4[kq * 16 + m16];       // L1/L2-hot (16 KB)
                int j0 = kq * 64 + m16 * 4;
                // diagonal j==i auto-excluded: cmpg[i] == ci
                if (cj.x != ci) e = umin64(e, pack_edge(w.x, i, j0));
                if (cj.y != ci) e = umin64(e, pack_edge(w.y, i, j0 + 1));
                if (cj.z != ci) e = umin64(e, pack_edge(w.z, i, j0 + 2));
                if (cj.w != ci) e = umin64(e, pack_edge(w.w, i, j0 + 3));
            }
            #pragma unroll
            for (int off = 8; off; off >>= 1)
                e = umin64(e, __shfl_down(e, (unsigned)off, 16));
            if (kq >= 0 && m16 == 0) {
                cnd[i * NCHUNK + kq] = e;            // ~0ull -> permanent
                extra = umin64(extra, e);
            }
        }
    }
    u64 rmin = wave_min64(umin64(live, extra));
    // pre-check: stale plain read >= current (best monotone decreasing) -> safe
    if (lane == 0 && rmin != ~0ull && rmin < bst[ci]) atomicMin(&bst[ci], rmin);
}

// One block (1024 threads) per problem: hook, break 2-cycles, accumulate
// deduped edge losses, RACY in-place pointer-jump (2 barriers/iter),
// relabel, reset best, set done, add loss. identity=1 for round 1.
__global__ __launch_bounds__(1024) void contract_k(
    const float* __restrict__ D1, const float* __restrict__ D2,
    u64* __restrict__ best, int* __restrict__ comp,
    int* __restrict__ done, float* __restrict__ out, int identity) {
    int pb = blockIdx.x;
    if (!identity && done[pb]) return;
    u64* __restrict__ bst = best + pb * NPTS;
    int* __restrict__ cmp = comp + pb * NPTS;

    __shared__ int link_s[NPTS];
    __shared__ float red_s[16];
    __shared__ int flag_s;
    int t = threadIdx.x;
    float loss = 0.f;

    int eu[4], ev[4], nl[4];
    bool act[4];

    for (int q = 0; q < 4; ++q) {
        int c = t + q * 1024;
        u64 b = bst[c];
        bool a = (b != ~0ull);
        act[q] = a;
        int u = (int)((b >> 12) & 0xFFF), v = (int)(b & 0xFFF);
        eu[q] = u; ev[q] = v;
        int l = c;
        if (a) {
            if (identity) l = (u == c) ? v : u;
            else { int cu = cmp[u]; l = (cu == c) ? cmp[v] : cu; }
        }
        link_s[c] = l;
    }
    __syncthreads();

    for (int q = 0; q < 4; ++q) {
        int c = t + q * 1024;
        int l = link_s[c];
        bool is2 = (l != c) && (link_s[l] == c);
        if (act[q] && !(is2 && c > l)) {
            size_t off = (size_t)eu[q] * NPTS + ev[q];
            float d = D1[off] - D2[off];
            loss += d * d;
        }
        nl[q] = (is2 && c < l) ? c : l;
    }
    __syncthreads();
    for (int q = 0; q < 4; ++q) link_s[t + q * 1024] = nl[q];
    __syncthreads();

    // Racy in-place pointer jumping: link is a forest (2-cycles broken);
    // link[c]=link[link[c]] with concurrent word-atomic LDS updates only
    // jumps toward roots. flag-exit exact: no change anywhere =>
    // link[link[c]]==link[c] for all c => all at roots.
    for (int it = 0; it < 13; ++it) {
        if (t == 0) flag_s = 0;
        __syncthreads();
        bool ch = false;
        for (int q = 0; q < 4; ++q) {
            int c = t + q * 1024;
            int l = link_s[c];
            int ll = link_s[l];
            if (ll != l) { link_s[c] = ll; ch = true; }
        }
        if (ch) flag_s = 1;
        __syncthreads();
        if (!flag_s) break;
    }

    int c0 = identity ? 0 : cmp[0];
    int root0 = link_s[c0];
    int same = 1;
    for (int q = 0; q < 4; ++q) {
        int v = t + q * 1024;
        int oc = identity ? v : cmp[v];
        int r = link_s[oc];
        cmp[v] = r;
        same &= (r == root0);
        bst[v] = ~0ull;
    }
    int all = __syncthreads_and(same);
    if (all && t == 0) done[pb] = 1;

    #pragma unroll
    for (int off = 32; off; off >>= 1) loss += __shfl_down(loss, (unsigned)off, 64);
    int wave = t >> 6, lane = t & 63;
    if (lane == 0) red_s[wave] = loss;
    __syncthreads();
    if (t == 0) {
        float s = 0.f;
        for (int wv = 0; wv < 16; ++wv) s += red_s[wv];
        atomicAdd(out, s);
    }
}

extern "C" void kernel_launch(void* const* d_in, const int* in_sizes, int n_in,
                              void* d_out, int out_size, void* d_ws, size_t ws_size,
                              hipStream_t stream) {
    const float* D1 = (const float*)d_in[0];   // input_distances  (4096x4096 f32)
    const float* D2 = (const float*)d_in[1];   // latent_distances (4096x4096 f32)
    float* out = (float*)d_out;

    char* ws = (char*)d_ws;
    u64* best = (u64*)ws;                          // 65536 B
    int* comp = (int*)(ws + 65536);                // 32768 B
    int* done = (int*)(ws + 65536 + 32768);        // 8 B
    u64* cand = (u64*)(ws + 98312);                // 4 MiB

    init_k<<<1, 1024, 0, stream>>>(best, done, out);
    tile_k<<<2 * NTRI, 256, 0, stream>>>(D1, D2, cand, best);
    contract_k<<<2, 1024, 0, stream>>>(D1, D2, best, comp, done, out, 1);
    for (int r = 1; r < ROUNDS; ++r) {
        warm_k<<<2 * NBLK, 256, 0, stream>>>(D1, D2, best, comp, done, cand);
        contract_k<<<2, 1024, 0, stream>>>(D1, D2, best, comp, done, out, 0);
    }
}

// Round 13
// 135.654 us; speedup vs baseline: 1.0389x; 1.0389x over previous
//
#include <hip/hip_runtime.h>
#include <stdint.h>

// TopoAELoss: two dense-graph MSTs (Boruvka) + sum of squared weight
// differences over both MST edge sets.
//
// R23: exact revert to the R21 configuration (best measured: 135.35us).
// R22 bundled two changes (triangular tile grid; finalize_k eliminated in
// favor of ~1M tile-side atomicMins + init_k) and regressed to 140.9us —
// likely the 65 serialized LLC RMWs per best[i] on tile_k's critical path
// + the extra serial init launch, vs the ~3us full-width finalize it
// replaced. Reverted wholesale; no new experiment bundled.
//
// Accumulated budget model (R13-R22 deltas): tile ~21us (66MB triangle at
// the ~3.1 TB/s read ceiling — byte-minimal), finalize ~3us, warm total
// ~35-45us (heavy rounds at their rescan byte floor), contract+boundaries
// ~45us (resisted 4 structural attacks: R18/R19 fusion pathology, R20
// fast-path regression, R22 finalize-elimination regression). Standing
// wins: R17 symmetry (-30us), R21 racy pointer-jump (-1us).
//
// R22 lesson: don't put per-row atomicMin chains on the cold-scan
// critical path; don't bundle two changes in one round.
// R21 lesson: racy in-place pointer jumping in contract is correct and
// slightly faster. Contract is ~2.5us/launch — small.
// R20 lesson: no dependent-load fast paths in front of slow-path rows.
// R19/R18 lesson: do NOT fuse contraction via last-block/arrival
// patterns — flat serial-tail pathology; graph launches are sub-us.
// R17 lesson: symmetric 64x64-tile cold scan halved cold bytes ->
// 166.5 -> 136.5us. ~3.1 TB/s is the empirical READ ceiling.
// R16 lesson: rank-2 candidate cache null (deaths correlated).
// R15 lesson: scan throughput tracks occupancy; keep VGPR small.
// R14 lesson: burst load hoisting regressed. Keep rolled loops.
// R13 lesson: ROUNDS must be 12 = ceil(log2(4096)) — harness re-poisons
// inputs for the post-timing check. NEVER lower below 12.
// R11 lesson: per-lane CONTIGUOUS global rescans destroy coalescing; any
// contiguous range must be read wave/quarter-cooperatively.
// R10 lesson: do NOT fuse contraction into the scan kernel.
//
// Layout of d_ws (~4.3 MiB):
//   best : 2*4096 u64  @ 0       (65536 B)
//   comp : 2*4096 i32  @ 65536   (32768 B)
//   done : 2     i32   @ 98304   (8 B)
//   cand : 2*4096*64 u64 @ 98312 (4 MiB)   per-(row,64col-chunk) best edge

#define NPTS 4096
#define NCHUNK 64                   // contiguous 64-col chunks per row
#define NBLK 1024                   // warm blocks per problem (4 rows each)
#define ROUNDS 12                   // ceil(log2(4096)) — sufficient for ANY
                                    // input. NEVER lower below 12.

typedef unsigned long long u64;

__device__ __forceinline__ u64 umin64(u64 a, u64 b) { return a < b ? a : b; }

// [ w_bits:32 | min(i,j):12 | max(i,j):12 ] — strict total order, symmetric.
__device__ __forceinline__ u64 pack_edge(float w, int i, int j) {
    unsigned wb = __float_as_uint(w);
    int u = i < j ? i : j;
    int v = i < j ? j : i;
    return ((u64)wb << 24) | ((u64)(unsigned)u << 12) | (u64)(unsigned)v;
}

__device__ __forceinline__ u64 wave_min64(u64 v) {
    #pragma unroll
    for (int off = 32; off; off >>= 1)
        v = umin64(v, __shfl_down(v, (unsigned)off, 64));
    return v;   // valid in lane 0
}

// Cold tile scan: one block per 64x64 tile (r<=c; lower tiles exit).
// Load tile to LDS (coalesced float4). wave0: per-row argmin ->
// cand[R0+l][c]. wave1 (r<c): per-col argmin -> cand[C0+l][r] (valid by
// symmetry). Diagonal tiles exclude j==i and skip wave1.
__global__ __launch_bounds__(256) void tile_k(
    const float* __restrict__ D1, const float* __restrict__ D2,
    u64* __restrict__ cand) {
    int pb = blockIdx.x >> 12;
    int t  = blockIdx.x & 4095;
    int r = t >> 6, c = t & 63;
    if (r > c) return;
    const float* __restrict__ D = pb ? D2 : D1;
    u64* __restrict__ cnd = cand + (size_t)pb * NPTS * NCHUNK;

    __shared__ float ts[64][65];    // pad 65: banks (row+col)%32 -> 2-way, free
    int R0 = r << 6, C0 = c << 6;
    int tid = threadIdx.x;

    #pragma unroll
    for (int e = 0; e < 4; ++e) {
        int idx4 = tid + e * 256;
        int row = idx4 >> 4, c4 = idx4 & 15;
        const float4* __restrict__ rp =
            (const float4*)(D + (size_t)(R0 + row) * NPTS + C0);
        float4 w = rp[c4];
        ts[row][c4 * 4    ] = w.x; ts[row][c4 * 4 + 1] = w.y;
        ts[row][c4 * 4 + 2] = w.z; ts[row][c4 * 4 + 3] = w.w;
    }
    __syncthreads();

    int wave = tid >> 6, lane = tid & 63;
    if (wave == 0) {
        int i = R0 + lane;
        float wm = 3.4e38f; int jm = 0;
        if (r == c) {
            for (int j = 0; j < 64; ++j) {
                float x = ts[lane][j];
                if ((C0 + j) != i && x < wm) { wm = x; jm = C0 + j; }
            }
        } else {
            for (int j = 0; j < 64; ++j) {
                float x = ts[lane][j];
                if (x < wm) { wm = x; jm = C0 + j; }
            }
        }
        cnd[i * NCHUNK + c] = pack_edge(wm, i, jm);
    } else if (wave == 1 && r != c) {
        int jcol = C0 + lane;
        float wm = 3.4e38f; int im = 0;
        for (int k2 = 0; k2 < 64; ++k2) {
            float x = ts[k2][lane];
            if (x < wm) { wm = x; im = R0 + k2; }
        }
        cnd[jcol * NCHUNK + r] = pack_edge(wm, jcol, im);
    }
}

// Reduce cand rows -> best (coalesced 512B read per row, one wave_min64).
// Also zeroes done[] and out[] (read only by later kernels).
__global__ __launch_bounds__(256) void finalize_k(
    u64* __restrict__ best, const u64* __restrict__ cand,
    int* __restrict__ done, float* __restrict__ out) {
    if (blockIdx.x == 0 && threadIdx.x == 0) {
        done[0] = 0; done[1] = 0; out[0] = 0.f;
    }
    int pb = blockIdx.x >> 10;
    int rb = blockIdx.x & (NBLK - 1);
    const u64* __restrict__ cnd = cand + (size_t)pb * NPTS * NCHUNK;
    int wave = threadIdx.x >> 6, lane = threadIdx.x & 63;
    int i = rb * 4 + wave;
    u64 bv = wave_min64(cnd[i * NCHUNK + lane]);
    if (lane == 0) best[pb * NPTS + i] = bv;   // identity comp: row-private
}

// Warm scan: 1 row per wave. Lane l validates cand[i][l] (far endpoint
// still external -> still exact; components only grow). Dead chunks are
// rescanned cooperatively: 4 chunks per pass, one quarter-wave each
// (16 lanes x float4 = 256B coalesced), 4-step shfl reduce, refresh cand.
// ~0ull rescan result = chunk permanently internal. One wave_min64/row.
__global__ __launch_bounds__(256) void warm_k(
    const float* __restrict__ D1, const float* __restrict__ D2,
    u64* __restrict__ best, const int* __restrict__ comp,
    const int* __restrict__ done, u64* __restrict__ cand) {
    int pb = blockIdx.x >> 10;
    if (done[pb]) return;
    int rb = blockIdx.x & (NBLK - 1);
    const float* __restrict__ D = pb ? D2 : D1;
    const int* __restrict__ cmpg = comp + pb * NPTS;
    u64* __restrict__ bst = best + pb * NPTS;
    u64* __restrict__ cnd = cand + (size_t)pb * NPTS * NCHUNK;

    int wave = threadIdx.x >> 6, lane = threadIdx.x & 63;
    int i = rb * 4 + wave;
    int ci = cmpg[i];

    u64 live = ~0ull;
    bool dead = false;
    u64 c = cnd[i * NCHUNK + lane];      // coalesced 64-lane load
    if (c != ~0ull) {                    // ~0ull: chunk permanently all-internal
        int u = (int)((c >> 12) & 0xFFF), v = (int)(c & 0xFFF);
        int j = (u == i) ? v : u;
        if (cmpg[j] != ci) live = c;     // still external -> still exact
        else dead = true;
    }

    u64 extra = ~0ull;
    u64 mask = __ballot(dead);           // wave-uniform
    if (mask) {
        const float4* __restrict__ rowf = (const float4*)(D + (size_t)i * NPTS);
        const int4* __restrict__ cmp4 = (const int4*)cmpg;
        int g = lane >> 4, m16 = lane & 15;
        while (mask) {
            int kq = -1;                 // chunk assigned to my quarter
            #pragma unroll
            for (int s = 0; s < 4; ++s) {
                int kk = mask ? (int)(__ffsll((long long)mask) - 1) : -1;
                if (kk >= 0) mask &= mask - 1;
                if (s == g) kq = kk;
            }
            u64 e = ~0ull;
            if (kq >= 0) {
                float4 w = rowf[kq * 16 + m16];      // 256B coalesced/quarter
                int4 cj = cmp4[kq * 16 + m16];       // L1/L2-hot (16 KB)
                int j0 = kq * 64 + m16 * 4;
                // diagonal j==i auto-excluded: cmpg[i] == ci
                if (cj.x != ci) e = umin64(e, pack_edge(w.x, i, j0));
                if (cj.y != ci) e = umin64(e, pack_edge(w.y, i, j0 + 1));
                if (cj.z != ci) e = umin64(e, pack_edge(w.z, i, j0 + 2));
                if (cj.w != ci) e = umin64(e, pack_edge(w.w, i, j0 + 3));
            }
            #pragma unroll
            for (int off = 8; off; off >>= 1)
                e = umin64(e, __shfl_down(e, (unsigned)off, 16));
            if (kq >= 0 && m16 == 0) {
                cnd[i * NCHUNK + kq] = e;            // ~0ull -> permanent
                extra = umin64(extra, e);
            }
        }
    }
    u64 rmin = wave_min64(umin64(live, extra));
    // pre-check: stale plain read >= current (best monotone decreasing) -> safe
    if (lane == 0 && rmin != ~0ull && rmin < bst[ci]) atomicMin(&bst[ci], rmin);
}

// One block (1024 threads) per problem: hook, break 2-cycles, accumulate
// deduped edge losses, RACY in-place pointer-jump (2 barriers/iter),
// relabel, reset best, set done, add loss. identity=1 for round 1.
__global__ __launch_bounds__(1024) void contract_k(
    const float* __restrict__ D1, const float* __restrict__ D2,
    u64* __restrict__ best, int* __restrict__ comp,
    int* __restrict__ done, float* __restrict__ out, int identity) {
    int pb = blockIdx.x;
    if (!identity && done[pb]) return;
    u64* __restrict__ bst = best + pb * NPTS;
    int* __restrict__ cmp = comp + pb * NPTS;

    __shared__ int link_s[NPTS];
    __shared__ float red_s[16];
    __shared__ int flag_s;
    int t = threadIdx.x;
    float loss = 0.f;

    int eu[4], ev[4], nl[4];
    bool act[4];

    for (int q = 0; q < 4; ++q) {
        int c = t + q * 1024;
        u64 b = bst[c];
        bool a = (b != ~0ull);
        act[q] = a;
        int u = (int)((b >> 12) & 0xFFF), v = (int)(b & 0xFFF);
        eu[q] = u; ev[q] = v;
        int l = c;
        if (a) {
            if (identity) l = (u == c) ? v : u;
            else { int cu = cmp[u]; l = (cu == c) ? cmp[v] : cu; }
        }
        link_s[c] = l;
    }
    __syncthreads();

    for (int q = 0; q < 4; ++q) {
        int c = t + q * 1024;
        int l = link_s[c];
        bool is2 = (l != c) && (link_s[l] == c);
        if (act[q] && !(is2 && c > l)) {
            size_t off = (size_t)eu[q] * NPTS + ev[q];
            float d = D1[off] - D2[off];
            loss += d * d;
        }
        nl[q] = (is2 && c < l) ? c : l;
    }
    __syncthreads();
    for (int q = 0; q < 4; ++q) link_s[t + q * 1024] = nl[q];
    __syncthreads();

    // Racy in-place pointer jumping: link is a forest (2-cycles broken);
    // link[c]=link[link[c]] with concurrent word-atomic LDS updates only
    // jumps toward roots. flag-exit exact: no change anywhere =>
    // link[link[c]]==link[c] for all c => all at roots.
    for (int it = 0; it < 13; ++it) {
        if (t == 0) flag_s = 0;
        __syncthreads();
        bool ch = false;
        for (int q = 0; q < 4; ++q) {
            int c = t + q * 1024;
            int l = link_s[c];
            int ll = link_s[l];
            if (ll != l) { link_s[c] = ll; ch = true; }
        }
        if (ch) flag_s = 1;
        __syncthreads();
        if (!flag_s) break;
    }

    int c0 = identity ? 0 : cmp[0];
    int root0 = link_s[c0];
    int same = 1;
    for (int q = 0; q < 4; ++q) {
        int v = t + q * 1024;
        int oc = identity ? v : cmp[v];
        int r = link_s[oc];
        cmp[v] = r;
        same &= (r == root0);
        bst[v] = ~0ull;
    }
    int all = __syncthreads_and(same);
    if (all && t == 0) done[pb] = 1;

    #pragma unroll
    for (int off = 32; off; off >>= 1) loss += __shfl_down(loss, (unsigned)off, 64);
    int wave = t >> 6, lane = t & 63;
    if (lane == 0) red_s[wave] = loss;
    __syncthreads();
    if (t == 0) {
        float s = 0.f;
        for (int wv = 0; wv < 16; ++wv) s += red_s[wv];
        atomicAdd(out, s);
    }
}

extern "C" void kernel_launch(void* const* d_in, const int* in_sizes, int n_in,
                              void* d_out, int out_size, void* d_ws, size_t ws_size,
                              hipStream_t stream) {
    const float* D1 = (const float*)d_in[0];   // input_distances  (4096x4096 f32)
    const float* D2 = (const float*)d_in[1];   // latent_distances (4096x4096 f32)
    float* out = (float*)d_out;

    char* ws = (char*)d_ws;
    u64* best = (u64*)ws;                          // 65536 B
    int* comp = (int*)(ws + 65536);                // 32768 B
    int* done = (int*)(ws + 65536 + 32768);        // 8 B
    u64* cand = (u64*)(ws + 98312);                // 4 MiB

    tile_k<<<2 * 4096, 256, 0, stream>>>(D1, D2, cand);
    finalize_k<<<2 * NBLK, 256, 0, stream>>>(best, cand, done, out);
    contract_k<<<2, 1024, 0, stream>>>(D1, D2, best, comp, done, out, 1);
    for (int r = 1; r < ROUNDS; ++r) {
        warm_k<<<2 * NBLK, 256, 0, stream>>>(D1, D2, best, comp, done, cand);
        contract_k<<<2, 1024, 0, stream>>>(D1, D2, best, comp, done, out, 0);
    }
}